// Round 9
// baseline (648.816 us; speedup 1.0000x reference)
//
#include <hip/hip_runtime.h>
#include <hip/hip_bf16.h>
#include <math.h>

#define PI_F 3.14159265358979323846f

#define NS   4
#define CIN  64
#define HH   128
#define WW   128
#define KXN  65          // rfft last-axis size
#define NPIX (HH*WW)
#define MMAT 1600        // CIN*5*5
#define NIT  8           // CG iterations

// float offsets in workspace (budget: 11,937,536 floats = 47.75 MB, proven)
#define OFF_SINV 0
#define OFF_E    33280
#define OFF_ER   98816
#define OFF_VR   231936
#define OFF_WB   298496
#define OFF_R    364032      // 4*64*64*81 = 1,327,104 floats -> ends 1,691,136
#define OFF_RP   1691136    // GEMM partials: 8 sl * 4 n * 41 s * 4096 = 5,373,952 -> ends 7,065,088
#define OFF_XB   7196160    // bf16 padded copies: 2*4,734,976 ushorts + guard
#define XB0C     4734976    // ushorts per copy (4*64*136*136)
// CG state reuses the (dead-by-then) front-end scratch at offset 0:
#define OFF_DV   0
#define OFF_RV   6400
#define OFF_PV   12800
#define OFF_AP   19200
#define OFF_RV2  25600      // double-buffer for r (iteration parity)
#define OFF_PAPP 32000      // [it*256 + n*64 + j] pAp partials (overlaps dead E region tail ok)

#define WRED(x) { (x)+=__shfl_down((x),32); (x)+=__shfl_down((x),16); (x)+=__shfl_down((x),8); \
                  (x)+=__shfl_down((x),4);  (x)+=__shfl_down((x),2);  (x)+=__shfl_down((x),1); }

typedef __attribute__((ext_vector_type(8))) short bf16x8;
typedef __attribute__((ext_vector_type(4))) float f32x4;

// ---------------------------------------------------------------------------
// Sinv[n,ky,kx] = 1 / (sum_c |D_c(ky,kx)|^2 + alpha_x/64)
// ---------------------------------------------------------------------------
__global__ __launch_bounds__(256) void k_sinv(const float* __restrict__ dict,
                                              const float* __restrict__ alpha_x,
                                              float* __restrict__ ws) {
  int idx = blockIdx.x * 256 + threadIdx.x;
  int n = blockIdx.y;
  if (idx >= HH * KXN) return;
  int ky = idx / KXN, kx = idx % KXN;
  float tr[25], ti[25];
  {
    float eyr[5], eyi[5], exr[5], exi[5];
#pragma unroll
    for (int a = 0; a < 5; ++a) {
      float s, c;
      sincosf(-2.0f * PI_F * (float)(ky * (a - 2)) / 128.0f, &s, &c);
      eyr[a] = c; eyi[a] = s;
      sincosf(-2.0f * PI_F * (float)(kx * (a - 2)) / 128.0f, &s, &c);
      exr[a] = c; exi[a] = s;
    }
#pragma unroll
    for (int a = 0; a < 5; ++a)
#pragma unroll
      for (int b = 0; b < 5; ++b) {
        tr[a*5+b] = eyr[a]*exr[b] - eyi[a]*exi[b];
        ti[a*5+b] = eyr[a]*exi[b] + eyi[a]*exr[b];
      }
  }
  const float* dn = dict + n * CIN * 25;
  float S = 0.0f;
  for (int c = 0; c < CIN; ++c) {
    const float* p = dn + c * 25;
    float Dr = 0.0f, Di = 0.0f;
#pragma unroll
    for (int t = 0; t < 25; ++t) { Dr += p[t]*tr[t]; Di += p[t]*ti[t]; }
    S += Dr*Dr + Di*Di;
  }
  float a = alpha_x[n] * (1.0f/64.0f);
  ws[OFF_SINV + (n*HH + ky)*KXN + kx] = 1.0f / (S + a);
}

// ---------------------------------------------------------------------------
// e[n,p] = y[n,p] - sum_c sum_{a,b} psf[n,c,a,b] * x[..circular..]
// ---------------------------------------------------------------------------
__global__ __launch_bounds__(256) void k_e(const float* __restrict__ x,
                                           const float* __restrict__ dict,
                                           const float* __restrict__ y,
                                           float* __restrict__ ws) {
  __shared__ float psf_s[CIN*25];
  __shared__ float xt[20*20];
  int n = blockIdx.y, tile = blockIdx.x, tid = threadIdx.x;
  int h0 = (tile >> 3) * 16, w0 = (tile & 7) * 16;
  for (int i = tid; i < CIN*25; i += 256) psf_s[i] = dict[n*CIN*25 + i];
  int py = tid >> 4, px = tid & 15;
  float acc = 0.0f;
  for (int c = 0; c < CIN; ++c) {
    __syncthreads();
    for (int i = tid; i < 400; i += 256) {
      int r = i / 20, cc = i % 20;
      int gh = (h0 + r - 2) & 127, gw = (w0 + cc - 2) & 127;
      xt[i] = x[((n*CIN + c)*HH + gh)*WW + gw];
    }
    __syncthreads();
    const float* pp = psf_s + c*25;
#pragma unroll
    for (int a = 0; a < 5; ++a)
#pragma unroll
      for (int b = 0; b < 5; ++b)
        acc += pp[a*5+b] * xt[(py+a)*20 + (px+b)];
  }
  int h = h0+py, w = w0+px;
  ws[OFF_E + (n*HH + h)*WW + w] = y[(n*HH + h)*WW + w] - acc;
}

// ---------------------------------------------------------------------------
// row DFT
// ---------------------------------------------------------------------------
__global__ __launch_bounds__(256) void k_fft_rows(float* __restrict__ ws) {
  __shared__ float twr[128], twi[128];
  int tid = threadIdx.x;
  if (tid < 128) { float s, c; sincosf(-2.0f*PI_F*(float)tid/128.0f, &s, &c); twr[tid]=c; twi[tid]=s; }
  __syncthreads();
  int idx = blockIdx.x*256 + tid, n = blockIdx.y;
  if (idx >= HH*KXN) return;
  int h = idx / KXN, k = idx % KXN;
  const float* row = ws + OFF_E + (n*HH + h)*WW;
  float sr = 0, si = 0;
  for (int w = 0; w < 128; ++w) {
    int t = (w*k) & 127;
    float v = row[w];
    sr += v*twr[t]; si += v*twi[t];
  }
  float* o = ws + OFF_ER + ((n*HH + h)*KXN + k)*2;
  o[0] = sr; o[1] = si;
}

// ---------------------------------------------------------------------------
// column pipeline: fwd DFT * Sinv, inverse DFT — column stays in LDS
// ---------------------------------------------------------------------------
__global__ __launch_bounds__(128) void k_fft_colpipe(float* __restrict__ ws) {
  __shared__ float twr[128], twi[128];
  __shared__ float ecr[128], eci[128];
  __shared__ float ewr[128], ewi[128];
  int tid = threadIdx.x;
  int kx = blockIdx.x, n = blockIdx.y;
  { float s, c; sincosf(-2.0f*PI_F*(float)tid/128.0f, &s, &c); twr[tid]=c; twi[tid]=s; }
  const float* Er = ws + OFF_ER + (size_t)n*HH*KXN*2;
  ecr[tid] = Er[(tid*KXN + kx)*2];
  eci[tid] = Er[(tid*KXN + kx)*2 + 1];
  __syncthreads();
  {
    int ky = tid;
    float sr = 0, si = 0;
    for (int h = 0; h < 128; ++h) {
      int t = (h*ky) & 127;
      float ar = ecr[h], ai = eci[h];
      sr += ar*twr[t] - ai*twi[t];
      si += ar*twi[t] + ai*twr[t];
    }
    float sv = ws[OFF_SINV + (n*HH + ky)*KXN + kx];
    ewr[ky] = sr*sv; ewi[ky] = si*sv;
  }
  __syncthreads();
  {
    int h = tid;
    float sr = 0, si = 0;
    for (int ky = 0; ky < 128; ++ky) {
      int t = (h*ky) & 127;
      float ar = ewr[ky], ai = ewi[ky];
      sr += ar*twr[t] + ai*twi[t];
      si += ai*twr[t] - ar*twi[t];
    }
    float* o = ws + OFF_VR + ((n*HH + h)*KXN + kx)*2;
    o[0] = sr; o[1] = si;
  }
}

__global__ __launch_bounds__(256) void k_ifft_rows(float* __restrict__ ws) {
  __shared__ float twr[128], twi[128];
  int tid = threadIdx.x;
  if (tid < 128) { float s, c; sincosf(-2.0f*PI_F*(float)tid/128.0f, &s, &c); twr[tid]=c; twi[tid]=s; }
  __syncthreads();
  int idx = blockIdx.x*256 + tid, n = blockIdx.y;
  int h = idx >> 7, w = idx & 127;
  const float* Vr = ws + OFF_VR + (size_t)n*HH*KXN*2;
  float s = 0.0f;
  for (int kx = 0; kx <= 64; ++kx) {
    int t = (w*kx) & 127;
    float ar = Vr[(h*KXN + kx)*2], ai = Vr[(h*KXN + kx)*2 + 1];
    float re = ar*twr[t] + ai*twi[t];
    s += (kx == 0 || kx == 64) ? re : 2.0f*re;
  }
  ws[OFF_WB + (n*HH + h)*WW + w] = s * (1.0f/16384.0f);
}

// ---------------------------------------------------------------------------
// x_new = x + psf (x) wbuf (circular correlate-back)
// ---------------------------------------------------------------------------
__global__ __launch_bounds__(256) void k_xnew(const float* __restrict__ x,
                                              const float* __restrict__ dict,
                                              const float* __restrict__ ws,
                                              float* __restrict__ out) {
  __shared__ float psf_s[CIN*25];
  __shared__ float wt[20*20];
  int n = blockIdx.y, tile = blockIdx.x, tid = threadIdx.x;
  int h0 = (tile >> 3) * 16, w0 = (tile & 7) * 16;
  for (int i = tid; i < CIN*25; i += 256) psf_s[i] = dict[n*CIN*25 + i];
  for (int i = tid; i < 400; i += 256) {
    int r = i / 20, cc = i % 20;
    int gh = (h0 + r - 2) & 127, gw = (w0 + cc - 2) & 127;
    wt[i] = ws[OFF_WB + (n*HH + gh)*WW + gw];
  }
  __syncthreads();
  int py = tid >> 4, px = tid & 15;
  int h = h0+py, w = w0+px;
  for (int c = 0; c < CIN; ++c) {
    float acc = 0.0f;
    const float* pp = psf_s + c*25;
#pragma unroll
    for (int a = 0; a < 5; ++a)
#pragma unroll
      for (int b = 0; b < 5; ++b)
        acc += pp[a*5+b] * wt[(py + 4 - a)*20 + (px + 4 - b)];
    int gi = ((n*CIN + c)*HH + h)*WW + w;
    out[gi] = x[gi] + acc;
  }
}

// ---------------------------------------------------------------------------
// k_pad: x_new -> zero-padded bf16 image, two copies (copy1 offset by one
// element so odd-v shifted reads are dword-aligned).
// ---------------------------------------------------------------------------
__global__ __launch_bounds__(256) void k_pad(const float* __restrict__ xn,
                                             float* __restrict__ ws) {
  ushort* xb0 = (ushort*)(ws + OFF_XB);
  ushort* xb1 = xb0 + XB0C;
  int ch = blockIdx.y;
  int idx = blockIdx.x*256 + threadIdx.x;
  if (ch == 0 && idx == 0) xb1[0] = 0;
  if (idx >= 136*136) return;
  int hp = idx / 136, wp = idx % 136;
  float v = 0.0f;
  if (hp >= 4 && hp < 132 && wp >= 4 && wp < 132)
    v = xn[(size_t)ch*NPIX + (hp-4)*128 + (wp-4)];
  __hip_bfloat16 b = __float2bfloat16(v);
  ushort bits = *(ushort*)&b;
  size_t o = (size_t)ch*18496 + idx;
  xb0[o] = bits;
  xb1[o + 1] = bits;
}

// ---------------------------------------------------------------------------
// k_gemm v3: one shift per block (grid 41 x 8 kslices x 4 n = 1312 blocks),
// explicit 1-deep prefetch. R_s[i,j] = sum_p Xi[p+delta_s] * Xj[p], MFMA bf16.
// ---------------------------------------------------------------------------
__device__ inline bf16x8 load_bf8(const ushort* p) {
  const uint* q = (const uint*)p;
  union { uint4 u; bf16x8 s; } cv;
  cv.u.x = q[0]; cv.u.y = q[1]; cv.u.z = q[2]; cv.u.w = q[3];
  return cv.s;
}

__global__ __launch_bounds__(256) void k_gemm(float* __restrict__ ws) {
  const ushort* xb0 = (const ushort*)(ws + OFF_XB);
  const ushort* xb1 = xb0 + XB0C;
  int g = blockIdx.x, sl = blockIdx.y, nn = blockIdx.z;
  int tid = threadIdx.x;
  int wv = tid >> 6, lane = tid & 63;
  int l16 = lane & 15, quad = lane >> 4;
  int i = wv*16 + l16;

  const ushort* baseA;
  {
    int uv = g + 40;
    int u = uv / 9, v = uv % 9;
    size_t cA = (size_t)(nn*64 + i)*18496 + u*136 + v;
    baseA = (v & 1) ? (xb1 + cA + 1) : (xb0 + cA);
  }
  const ushort* baseB[4];
#pragma unroll
  for (int t = 0; t < 4; ++t)
    baseB[t] = xb0 + (size_t)(nn*64 + t*16 + l16)*18496 + 4*136 + 4;

  f32x4 acc[4];
#pragma unroll
  for (int t = 0; t < 4; ++t) acc[t] = (f32x4){0.f,0.f,0.f,0.f};

  int k0 = sl*2048 + quad*8;
  auto offs = [](int p)->int { int h = p >> 7; return (h << 7) + (h << 3) + (p & 127); };

  int hc = offs(k0);
  bf16x8 a_c = load_bf8(baseA + hc);
  bf16x8 b_c0 = load_bf8(baseB[0] + hc);
  bf16x8 b_c1 = load_bf8(baseB[1] + hc);
  bf16x8 b_c2 = load_bf8(baseB[2] + hc);
  bf16x8 b_c3 = load_bf8(baseB[3] + hc);
  for (int kt = 0; kt < 64; ++kt) {
    int hn = offs(k0 + ((kt+1) & 63)*32);
    bf16x8 a_n = load_bf8(baseA + hn);
    bf16x8 b_n0 = load_bf8(baseB[0] + hn);
    bf16x8 b_n1 = load_bf8(baseB[1] + hn);
    bf16x8 b_n2 = load_bf8(baseB[2] + hn);
    bf16x8 b_n3 = load_bf8(baseB[3] + hn);
    acc[0] = __builtin_amdgcn_mfma_f32_16x16x32_bf16(a_c, b_c0, acc[0], 0, 0, 0);
    acc[1] = __builtin_amdgcn_mfma_f32_16x16x32_bf16(a_c, b_c1, acc[1], 0, 0, 0);
    acc[2] = __builtin_amdgcn_mfma_f32_16x16x32_bf16(a_c, b_c2, acc[2], 0, 0, 0);
    acc[3] = __builtin_amdgcn_mfma_f32_16x16x32_bf16(a_c, b_c3, acc[3], 0, 0, 0);
    a_c = a_n; b_c0 = b_n0; b_c1 = b_n1; b_c2 = b_n2; b_c3 = b_n3;
  }

  float* Rp = ws + OFF_RP;
  size_t base = ((size_t)(sl*4 + nn)*41 + g)*4096;
#pragma unroll
  for (int t = 0; t < 4; ++t) {
#pragma unroll
    for (int r = 0; r < 4; ++r) {
      int iout = wv*16 + quad*4 + r;
      int jout = t*16 + l16;
      Rp[base + iout*64 + jout] = acc[t][r];
    }
  }
}

// ---------------------------------------------------------------------------
// k_rmerge: sum 8 k-slices; fill both symmetric halves of R.
// ---------------------------------------------------------------------------
__global__ __launch_bounds__(256) void k_rmerge(float* __restrict__ ws) {
  int idx = blockIdx.x*256 + threadIdx.x;    // 1,327,104 total
  int uv = idx % 81;
  int rem = idx / 81;
  int j = rem & 63;
  int i = (rem >> 6) & 63;
  int n = rem >> 12;
  int s, si, sj;
  if (uv >= 40) { s = uv - 40; si = i; sj = j; }
  else          { s = 40 - uv; si = j; sj = i; }
  const float* Rp = ws + OFF_RP;
  float v = 0.0f;
#pragma unroll
  for (int sl = 0; sl < 8; ++sl)
    v += Rp[((size_t)(sl*4 + n)*41 + s)*4096 + si*64 + sj];
  ws[OFF_R + idx] = v;
}

// ---------------------------------------------------------------------------
// Pm -> CG initial state: RV = PV = Pm (rr computed in-block by CG steps)
// ---------------------------------------------------------------------------
__global__ __launch_bounds__(256) void k_pm(const float* __restrict__ xn,
                                            const float* __restrict__ y,
                                            const float* __restrict__ dict,
                                            const float* __restrict__ alpha_d,
                                            const float* __restrict__ regp,
                                            float* __restrict__ ws) {
  __shared__ float xt[20*20];
  __shared__ float red_s[4][25];
  int n = blockIdx.y, i = blockIdx.x, tid = threadIdx.x;
  int py = tid >> 4, px = tid & 15;
  float acc[25];
#pragma unroll
  for (int t = 0; t < 25; ++t) acc[t] = 0.0f;
  const float* Xi = xn + (size_t)(n*CIN + i)*NPIX;
  for (int tile = 0; tile < 64; ++tile) {
    int h0 = (tile >> 3)*16, w0 = (tile & 7)*16;
    __syncthreads();
    for (int t = tid; t < 400; t += 256) {
      int r = t / 20, cc = t % 20;
      int gh = h0 + r - 2, gw = w0 + cc - 2;
      float v = 0.0f;
      if (gh >= 0 && gh < 128 && gw >= 0 && gw < 128) v = Xi[gh*128 + gw];
      xt[t] = v;
    }
    __syncthreads();
    float yv = y[(n*HH + h0 + py)*WW + w0 + px];
#pragma unroll
    for (int u = 0; u < 5; ++u)
#pragma unroll
      for (int v = 0; v < 5; ++v)
        acc[u*5+v] += xt[(py+u)*20 + (px+v)] * yv;
  }
  int lane = tid & 63, wv = tid >> 6;
#pragma unroll
  for (int t = 0; t < 25; ++t) {
    float v = acc[t];
    WRED(v);
    if (lane == 0) red_s[wv][t] = v;
  }
  __syncthreads();
  if (tid < 25) {
    float s = red_s[0][tid] + red_s[1][tid] + red_s[2][tid] + red_s[3][tid];
    float ad = alpha_d[n] * 16384.0f * regp[0] * (1.0f/1600.0f);
    float val = s + ad * dict[(n*CIN + i)*25 + tid];
    int idx = n*MMAT + i*25 + tid;
    ws[OFF_RV + idx] = val;
    ws[OFF_PV + idx] = val;
  }
}

// ---------------------------------------------------------------------------
// CG: k_cg_first computes Ap0 + pAp0 partials (per j, no atomics).
// ---------------------------------------------------------------------------
__global__ __launch_bounds__(256) void k_cg_first(float* __restrict__ ws,
                                                  const float* __restrict__ alpha_d,
                                                  const float* __restrict__ regp) {
  __shared__ float vv[MMAT];
  __shared__ float part[25][66];
  int n = blockIdx.y, j = blockIdx.x, tid = threadIdx.x;
  for (int t = tid; t < MMAT; t += 256) vv[t] = ws[OFF_PV + n*MMAT + t];
  __syncthreads();
  int i = tid & 63, qq = tid >> 6;
  const float* Rij = ws + OFF_R + (((size_t)n*CIN + i)*CIN + j)*81;
  const float* vi = &vv[i*25];
#pragma unroll
  for (int s6 = 0; s6 < 7; ++s6) {
    int ac = qq + 4*s6;
    if (ac < 25) {
      int a = ac/5, c = ac%5;
      float s = 0.0f;
#pragma unroll
      for (int b = 0; b < 5; ++b)
#pragma unroll
        for (int d = 0; d < 5; ++d)
          s += Rij[(4+b-a)*9 + (4+d-c)] * vi[b*5+d];
      part[ac][i] = s;
    }
  }
  __syncthreads();
  float contrib = 0.0f;
  if (tid < 25) {
    float s = 0.0f;
    for (int t = 0; t < 64; ++t) s += part[tid][t];
    float reg = alpha_d[n] * 16384.0f * regp[0] * (1.0f/1600.0f);
    s += reg * vv[j*25 + tid];
    ws[OFF_AP + n*MMAT + j*25 + tid] = s;
    contrib = s * vv[j*25 + tid];
  }
  if (tid < 64) {
    WRED(contrib);
    if (tid == 0) ws[OFF_PAPP + 0*256 + n*64 + j] = contrib;
  }
}

// ---------------------------------------------------------------------------
// Fused CG step: each (n,j) block holds full r in LDS; computes rr, alpha,
// r_new, rr_new, beta in-block (identical across blocks); matvec A r_new;
// updates its 25-element segments of p, Ap, d, r(other buffer); pAp partial.
// RV double-buffered by iteration parity (read cur, write other) -> race-free.
// ---------------------------------------------------------------------------
__global__ __launch_bounds__(256) void k_cg_step(float* __restrict__ ws, int it,
                                                 int last, float* __restrict__ out,
                                                 const float* __restrict__ alpha_d,
                                                 const float* __restrict__ regp) {
  __shared__ float vv[MMAT];       // r_new
  __shared__ float red_s[9];
  __shared__ float part[25][66];
  int n = blockIdx.y, j = blockIdx.x, tid = threadIdx.x;
  const float* rsrc = ws + ((it & 1) ? OFF_RV2 : OFF_RV) + n*MMAT;
  float*       rdst = ws + ((it & 1) ? OFF_RV  : OFF_RV2) + n*MMAT;
  int lane = tid & 63, wvi = tid >> 6;

  // load r_old, Ap; rr_old partial
  float rold[7], apv[7];
  float rrp = 0.0f;
#pragma unroll
  for (int t = 0; t < 7; ++t) {
    int idx = tid + 256*t;
    rold[t] = 0.0f; apv[t] = 0.0f;
    if (idx < MMAT) {
      rold[t] = rsrc[idx];
      apv[t]  = ws[OFF_AP + n*MMAT + idx];
      rrp += rold[t]*rold[t];
    }
  }
  WRED(rrp);
  if (lane == 0) red_s[wvi] = rrp;
  // pAp from partials (wave 0 reduces 64 slots)
  float pp = (tid < 64) ? ws[OFF_PAPP + it*256 + n*64 + tid] : 0.0f;
  if (tid < 64) { WRED(pp); if (tid == 0) red_s[4] = pp; }
  __syncthreads();
  float rr_old = red_s[0] + red_s[1] + red_s[2] + red_s[3];
  float alpha = rr_old / (red_s[4] + 1e-30f);

  if (last) {    // only the d-update + output write remain
    if (tid < 25) {
      int idx = n*MMAT + j*25 + tid;
      float dv = ws[OFF_DV + idx] + alpha * ws[OFF_PV + idx];
      out[4194304 + n*MMAT + j*25 + tid] = dv;
    }
    return;
  }

  // r_new into LDS + rr_new partial
  float rrnp = 0.0f;
#pragma unroll
  for (int t = 0; t < 7; ++t) {
    int idx = tid + 256*t;
    if (idx < MMAT) {
      float rn = rold[t] - alpha * apv[t];
      vv[idx] = rn;
      rrnp += rn*rn;
    }
  }
  WRED(rrnp);
  if (lane == 0) red_s[5 + wvi%4] = 0.0f;   // placeholder to keep LDS defined
  __syncthreads();                           // vv complete
  if (lane == 0) red_s[5 + wvi] = rrnp;      // separate slots per wave (5..8? only 4 waves)
  __syncthreads();
  float rr_new = red_s[5] + red_s[6] + red_s[7] + red_s[8];
  float beta = rr_new / (rr_old + 1e-30f);

  // matvec s = (A r_new) on segment j
  int i = tid & 63, qq = tid >> 6;
  const float* Rij = ws + OFF_R + (((size_t)n*CIN + i)*CIN + j)*81;
  const float* vi = &vv[i*25];
#pragma unroll
  for (int s6 = 0; s6 < 7; ++s6) {
    int ac = qq + 4*s6;
    if (ac < 25) {
      int a = ac/5, c = ac%5;
      float s = 0.0f;
#pragma unroll
      for (int b = 0; b < 5; ++b)
#pragma unroll
        for (int d = 0; d < 5; ++d)
          s += Rij[(4+b-a)*9 + (4+d-c)] * vi[b*5+d];
      part[ac][i] = s;
    }
  }
  __syncthreads();
  float contrib = 0.0f;
  if (tid < 25) {
    float s = 0.0f;
    for (int t = 0; t < 64; ++t) s += part[tid][t];
    float reg = alpha_d[n] * 16384.0f * regp[0] * (1.0f/1600.0f);
    float rn_seg = vv[j*25 + tid];
    s += reg * rn_seg;                       // s = (Q r_new)[seg]
    int idx = n*MMAT + j*25 + tid;
    float p_old = ws[OFF_PV + idx];
    float dv = ws[OFF_DV + idx] + alpha * p_old;
    float pn  = rn_seg + beta * p_old;
    float apn = s + beta * ws[OFF_AP + idx];
    ws[OFF_DV + idx] = dv;
    ws[OFF_PV + idx] = pn;
    ws[OFF_AP + idx] = apn;
    rdst[j*25 + tid] = rn_seg;
    contrib = pn * apn;
  }
  if (tid < 64) {
    WRED(contrib);
    if (tid == 0) ws[OFF_PAPP + (it+1)*256 + n*64 + j] = contrib;
  }
}

// ---------------------------------------------------------------------------
extern "C" void kernel_launch(void* const* d_in, const int* in_sizes, int n_in,
                              void* d_out, int out_size, void* d_ws, size_t ws_size,
                              hipStream_t stream) {
  (void)in_sizes; (void)n_in; (void)out_size; (void)ws_size;
  const float* x    = (const float*)d_in[0];
  const float* dict = (const float*)d_in[1];
  const float* y    = (const float*)d_in[2];
  const float* ax   = (const float*)d_in[3];
  const float* ad   = (const float*)d_in[4];
  const float* regp = (const float*)d_in[5];
  float* out = (float*)d_out;
  float* ws  = (float*)d_ws;

  dim3 b256(256);
  k_sinv<<<dim3(33,4), b256, 0, stream>>>(dict, ax, ws);
  k_e<<<dim3(64,4), b256, 0, stream>>>(x, dict, y, ws);
  k_fft_rows<<<dim3(33,4), b256, 0, stream>>>(ws);
  k_fft_colpipe<<<dim3(65,4), dim3(128), 0, stream>>>(ws);
  k_ifft_rows<<<dim3(64,4), b256, 0, stream>>>(ws);
  k_xnew<<<dim3(64,4), b256, 0, stream>>>(x, dict, ws, out);

  // ---- R via MFMA ----
  k_pad<<<dim3(73,256), b256, 0, stream>>>(out, ws);
  k_gemm<<<dim3(41,8,4), b256, 0, stream>>>(ws);
  k_rmerge<<<dim3(5184), b256, 0, stream>>>(ws);

  k_pm<<<dim3(64,4), b256, 0, stream>>>(out, y, dict, ad, regp, ws);

  // ---- CG (fused steps; 9 launches) ----
  k_cg_first<<<dim3(64,4), b256, 0, stream>>>(ws, ad, regp);
  for (int it = 0; it < NIT; ++it)
    k_cg_step<<<dim3(64,4), b256, 0, stream>>>(ws, it, (it == NIT-1) ? 1 : 0, out, ad, regp);
}

// Round 10
// 470.126 us; speedup vs baseline: 1.3801x; 1.3801x over previous
//
#include <hip/hip_runtime.h>
#include <hip/hip_bf16.h>
#include <math.h>

#define PI_F 3.14159265358979323846f

#define NS   4
#define CIN  64
#define HH   128
#define WW   128
#define KXN  65          // rfft last-axis size
#define NPIX (HH*WW)
#define MMAT 1600        // CIN*5*5
#define NIT  6           // CG iterations (rate ~0.32/iter; floor is fp32 front-end)

// float offsets in workspace (budget: 11,937,536 floats = 47.75 MB, proven)
#define OFF_SINV 0
#define OFF_E    33280
#define OFF_ER   98816
#define OFF_VR   231936
#define OFF_WB   298496
#define OFF_R    364032      // 4*64*64*81 = 1,327,104 floats -> ends 1,691,136
#define OFF_RP   1691136    // Rstage: 4 n * 41 s * 4096 = 671,744 floats -> ends 2,362,880
#define RSTN     167936     // float4 count of Rstage
#define OFF_XB   7196160    // bf16 padded copies: 2*4,734,976 ushorts + guard
#define XB0C     4734976    // ushorts per copy (4*64*136*136)
// CG state reuses the (dead-by-then) front-end scratch at offset 0:
#define OFF_DV   0
#define OFF_RV   6400
#define OFF_PV   12800
#define OFF_AP   19200
#define OFF_RV2  25600      // double-buffer for r (iteration parity)
#define OFF_PAPP 32000      // [it*256 + n*64 + j] pAp partials

#define WRED(x) { (x)+=__shfl_down((x),32); (x)+=__shfl_down((x),16); (x)+=__shfl_down((x),8); \
                  (x)+=__shfl_down((x),4);  (x)+=__shfl_down((x),2);  (x)+=__shfl_down((x),1); }

typedef __attribute__((ext_vector_type(8))) short bf16x8;
typedef __attribute__((ext_vector_type(4))) float f32x4;

// ---------------------------------------------------------------------------
// Sinv[n,ky,kx] = 1 / (sum_c |D_c(ky,kx)|^2 + alpha_x/64)
// ---------------------------------------------------------------------------
__global__ __launch_bounds__(256) void k_sinv(const float* __restrict__ dict,
                                              const float* __restrict__ alpha_x,
                                              float* __restrict__ ws) {
  int idx = blockIdx.x * 256 + threadIdx.x;
  int n = blockIdx.y;
  if (idx >= HH * KXN) return;
  int ky = idx / KXN, kx = idx % KXN;
  float tr[25], ti[25];
  {
    float eyr[5], eyi[5], exr[5], exi[5];
#pragma unroll
    for (int a = 0; a < 5; ++a) {
      float s, c;
      sincosf(-2.0f * PI_F * (float)(ky * (a - 2)) / 128.0f, &s, &c);
      eyr[a] = c; eyi[a] = s;
      sincosf(-2.0f * PI_F * (float)(kx * (a - 2)) / 128.0f, &s, &c);
      exr[a] = c; exi[a] = s;
    }
#pragma unroll
    for (int a = 0; a < 5; ++a)
#pragma unroll
      for (int b = 0; b < 5; ++b) {
        tr[a*5+b] = eyr[a]*exr[b] - eyi[a]*exi[b];
        ti[a*5+b] = eyr[a]*exi[b] + eyi[a]*exr[b];
      }
  }
  const float* dn = dict + n * CIN * 25;
  float S = 0.0f;
  for (int c = 0; c < CIN; ++c) {
    const float* p = dn + c * 25;
    float Dr = 0.0f, Di = 0.0f;
#pragma unroll
    for (int t = 0; t < 25; ++t) { Dr += p[t]*tr[t]; Di += p[t]*ti[t]; }
    S += Dr*Dr + Di*Di;
  }
  float a = alpha_x[n] * (1.0f/64.0f);
  ws[OFF_SINV + (n*HH + ky)*KXN + kx] = 1.0f / (S + a);
}

// ---------------------------------------------------------------------------
// e[n,p] = y[n,p] - sum_c sum_{a,b} psf[n,c,a,b] * x[..circular..]
// ---------------------------------------------------------------------------
__global__ __launch_bounds__(256) void k_e(const float* __restrict__ x,
                                           const float* __restrict__ dict,
                                           const float* __restrict__ y,
                                           float* __restrict__ ws) {
  __shared__ float psf_s[CIN*25];
  __shared__ float xt[20*20];
  int n = blockIdx.y, tile = blockIdx.x, tid = threadIdx.x;
  int h0 = (tile >> 3) * 16, w0 = (tile & 7) * 16;
  for (int i = tid; i < CIN*25; i += 256) psf_s[i] = dict[n*CIN*25 + i];
  int py = tid >> 4, px = tid & 15;
  float acc = 0.0f;
  for (int c = 0; c < CIN; ++c) {
    __syncthreads();
    for (int i = tid; i < 400; i += 256) {
      int r = i / 20, cc = i % 20;
      int gh = (h0 + r - 2) & 127, gw = (w0 + cc - 2) & 127;
      xt[i] = x[((n*CIN + c)*HH + gh)*WW + gw];
    }
    __syncthreads();
    const float* pp = psf_s + c*25;
#pragma unroll
    for (int a = 0; a < 5; ++a)
#pragma unroll
      for (int b = 0; b < 5; ++b)
        acc += pp[a*5+b] * xt[(py+a)*20 + (px+b)];
  }
  int h = h0+py, w = w0+px;
  ws[OFF_E + (n*HH + h)*WW + w] = y[(n*HH + h)*WW + w] - acc;
}

// ---------------------------------------------------------------------------
// row DFT
// ---------------------------------------------------------------------------
__global__ __launch_bounds__(256) void k_fft_rows(float* __restrict__ ws) {
  __shared__ float twr[128], twi[128];
  int tid = threadIdx.x;
  if (tid < 128) { float s, c; sincosf(-2.0f*PI_F*(float)tid/128.0f, &s, &c); twr[tid]=c; twi[tid]=s; }
  __syncthreads();
  int idx = blockIdx.x*256 + tid, n = blockIdx.y;
  if (idx >= HH*KXN) return;
  int h = idx / KXN, k = idx % KXN;
  const float* row = ws + OFF_E + (n*HH + h)*WW;
  float sr = 0, si = 0;
  for (int w = 0; w < 128; ++w) {
    int t = (w*k) & 127;
    float v = row[w];
    sr += v*twr[t]; si += v*twi[t];
  }
  float* o = ws + OFF_ER + ((n*HH + h)*KXN + k)*2;
  o[0] = sr; o[1] = si;
}

// ---------------------------------------------------------------------------
// column pipeline: fwd DFT * Sinv, inverse DFT — column stays in LDS
// ---------------------------------------------------------------------------
__global__ __launch_bounds__(128) void k_fft_colpipe(float* __restrict__ ws) {
  __shared__ float twr[128], twi[128];
  __shared__ float ecr[128], eci[128];
  __shared__ float ewr[128], ewi[128];
  int tid = threadIdx.x;
  int kx = blockIdx.x, n = blockIdx.y;
  { float s, c; sincosf(-2.0f*PI_F*(float)tid/128.0f, &s, &c); twr[tid]=c; twi[tid]=s; }
  const float* Er = ws + OFF_ER + (size_t)n*HH*KXN*2;
  ecr[tid] = Er[(tid*KXN + kx)*2];
  eci[tid] = Er[(tid*KXN + kx)*2 + 1];
  __syncthreads();
  {
    int ky = tid;
    float sr = 0, si = 0;
    for (int h = 0; h < 128; ++h) {
      int t = (h*ky) & 127;
      float ar = ecr[h], ai = eci[h];
      sr += ar*twr[t] - ai*twi[t];
      si += ar*twi[t] + ai*twr[t];
    }
    float sv = ws[OFF_SINV + (n*HH + ky)*KXN + kx];
    ewr[ky] = sr*sv; ewi[ky] = si*sv;
  }
  __syncthreads();
  {
    int h = tid;
    float sr = 0, si = 0;
    for (int ky = 0; ky < 128; ++ky) {
      int t = (h*ky) & 127;
      float ar = ewr[ky], ai = ewi[ky];
      sr += ar*twr[t] + ai*twi[t];
      si += ai*twr[t] - ar*twi[t];
    }
    float* o = ws + OFF_VR + ((n*HH + h)*KXN + kx)*2;
    o[0] = sr; o[1] = si;
  }
}

__global__ __launch_bounds__(256) void k_ifft_rows(float* __restrict__ ws) {
  __shared__ float twr[128], twi[128];
  int tid = threadIdx.x;
  if (tid < 128) { float s, c; sincosf(-2.0f*PI_F*(float)tid/128.0f, &s, &c); twr[tid]=c; twi[tid]=s; }
  __syncthreads();
  int idx = blockIdx.x*256 + tid, n = blockIdx.y;
  int h = idx >> 7, w = idx & 127;
  const float* Vr = ws + OFF_VR + (size_t)n*HH*KXN*2;
  float s = 0.0f;
  for (int kx = 0; kx <= 64; ++kx) {
    int t = (w*kx) & 127;
    float ar = Vr[(h*KXN + kx)*2], ai = Vr[(h*KXN + kx)*2 + 1];
    float re = ar*twr[t] + ai*twi[t];
    s += (kx == 0 || kx == 64) ? re : 2.0f*re;
  }
  ws[OFF_WB + (n*HH + h)*WW + w] = s * (1.0f/16384.0f);
}

// ---------------------------------------------------------------------------
// x_new = x + psf (x) wbuf (circular correlate-back)
// ---------------------------------------------------------------------------
__global__ __launch_bounds__(256) void k_xnew(const float* __restrict__ x,
                                              const float* __restrict__ dict,
                                              const float* __restrict__ ws,
                                              float* __restrict__ out) {
  __shared__ float psf_s[CIN*25];
  __shared__ float wt[20*20];
  int n = blockIdx.y, tile = blockIdx.x, tid = threadIdx.x;
  int h0 = (tile >> 3) * 16, w0 = (tile & 7) * 16;
  for (int i = tid; i < CIN*25; i += 256) psf_s[i] = dict[n*CIN*25 + i];
  for (int i = tid; i < 400; i += 256) {
    int r = i / 20, cc = i % 20;
    int gh = (h0 + r - 2) & 127, gw = (w0 + cc - 2) & 127;
    wt[i] = ws[OFF_WB + (n*HH + gh)*WW + gw];
  }
  __syncthreads();
  int py = tid >> 4, px = tid & 15;
  int h = h0+py, w = w0+px;
  for (int c = 0; c < CIN; ++c) {
    float acc = 0.0f;
    const float* pp = psf_s + c*25;
#pragma unroll
    for (int a = 0; a < 5; ++a)
#pragma unroll
      for (int b = 0; b < 5; ++b)
        acc += pp[a*5+b] * wt[(py + 4 - a)*20 + (px + 4 - b)];
    int gi = ((n*CIN + c)*HH + h)*WW + w;
    out[gi] = x[gi] + acc;
  }
}

// ---------------------------------------------------------------------------
// k_pad: x_new -> zero-padded bf16 image, two copies (copy1 offset by one
// element so odd-v shifted reads are dword-aligned).
// ---------------------------------------------------------------------------
__global__ __launch_bounds__(256) void k_pad(const float* __restrict__ xn,
                                             float* __restrict__ ws) {
  ushort* xb0 = (ushort*)(ws + OFF_XB);
  ushort* xb1 = xb0 + XB0C;
  int ch = blockIdx.y;
  int idx = blockIdx.x*256 + threadIdx.x;
  if (ch == 0 && idx == 0) xb1[0] = 0;
  if (idx >= 136*136) return;
  int hp = idx / 136, wp = idx % 136;
  float v = 0.0f;
  if (hp >= 4 && hp < 132 && wp >= 4 && wp < 132)
    v = xn[(size_t)ch*NPIX + (hp-4)*128 + (wp-4)];
  __hip_bfloat16 b = __float2bfloat16(v);
  ushort bits = *(ushort*)&b;
  size_t o = (size_t)ch*18496 + idx;
  xb0[o] = bits;
  xb1[o + 1] = bits;
}

// ---------------------------------------------------------------------------
// k_rzero: zero the compact Rstage accumulator (atomicAdd target)
// ---------------------------------------------------------------------------
__global__ __launch_bounds__(256) void k_rzero(float* __restrict__ ws) {
  int idx = blockIdx.x*256 + threadIdx.x;
  if (idx < RSTN)
    reinterpret_cast<float4*>(ws + OFF_RP)[idx] = make_float4(0.f, 0.f, 0.f, 0.f);
}

// ---------------------------------------------------------------------------
// k_gemm v4: s=4 shifts x t=4 j-tiles per block (16 MFMA / 8 loads = 2.0),
// 16 K-slices -> grid (11,16,4) = 704 blocks = 2.75/CU balanced.
// Blocks atomicAdd their 64x64 tile into pre-zeroed Rstage[n][41][4096].
// ---------------------------------------------------------------------------
__device__ inline bf16x8 load_bf8(const ushort* p) {
  const uint* q = (const uint*)p;
  union { uint4 u; bf16x8 s; } cv;
  cv.u.x = q[0]; cv.u.y = q[1]; cv.u.z = q[2]; cv.u.w = q[3];
  return cv.s;
}

__global__ __launch_bounds__(256) void k_gemm(float* __restrict__ ws) {
  const ushort* xb0 = (const ushort*)(ws + OFF_XB);
  const ushort* xb1 = xb0 + XB0C;
  int g = blockIdx.x, sl = blockIdx.y, nn = blockIdx.z;
  int tid = threadIdx.x;
  int wv = tid >> 6, lane = tid & 63;
  int l16 = lane & 15, quad = lane >> 4;
  int i = wv*16 + l16;

  const ushort* baseA[4];
  int svalid[4];
#pragma unroll
  for (int s = 0; s < 4; ++s) {
    int sidx = 4*g + s;
    svalid[s] = (sidx <= 40);
    if (sidx > 40) sidx = 40;
    int uv = sidx + 40;
    int u = uv / 9, v = uv % 9;
    size_t cA = (size_t)(nn*64 + i)*18496 + u*136 + v;
    baseA[s] = (v & 1) ? (xb1 + cA + 1) : (xb0 + cA);
  }
  const ushort* baseB[4];
#pragma unroll
  for (int t = 0; t < 4; ++t)
    baseB[t] = xb0 + (size_t)(nn*64 + t*16 + l16)*18496 + 4*136 + 4;

  f32x4 acc[4][4];
#pragma unroll
  for (int s = 0; s < 4; ++s)
#pragma unroll
    for (int t = 0; t < 4; ++t) acc[s][t] = (f32x4){0.f,0.f,0.f,0.f};

  int k0 = sl*1024 + quad*8;
  auto offs = [](int p)->int { int h = p >> 7; return (h << 7) + (h << 3) + (p & 127); };

  int hc = offs(k0);
  bf16x8 a_c[4], b_c[4];
#pragma unroll
  for (int s = 0; s < 4; ++s) a_c[s] = load_bf8(baseA[s] + hc);
#pragma unroll
  for (int t = 0; t < 4; ++t) b_c[t] = load_bf8(baseB[t] + hc);

  for (int kt = 0; kt < 32; ++kt) {
    int hn = offs(k0 + ((kt+1) & 31)*32);
    bf16x8 a_n[4], b_n[4];
#pragma unroll
    for (int s = 0; s < 4; ++s) a_n[s] = load_bf8(baseA[s] + hn);
#pragma unroll
    for (int t = 0; t < 4; ++t) b_n[t] = load_bf8(baseB[t] + hn);
#pragma unroll
    for (int s = 0; s < 4; ++s)
#pragma unroll
      for (int t = 0; t < 4; ++t)
        acc[s][t] = __builtin_amdgcn_mfma_f32_16x16x32_bf16(a_c[s], b_c[t], acc[s][t], 0, 0, 0);
#pragma unroll
    for (int s = 0; s < 4; ++s) a_c[s] = a_n[s];
#pragma unroll
    for (int t = 0; t < 4; ++t) b_c[t] = b_n[t];
  }

  float* Rs = ws + OFF_RP;
#pragma unroll
  for (int s = 0; s < 4; ++s) {
    if (!svalid[s]) continue;
    size_t base = ((size_t)nn*41 + (4*g + s))*4096;
#pragma unroll
    for (int t = 0; t < 4; ++t) {
#pragma unroll
      for (int r = 0; r < 4; ++r) {
        int iout = wv*16 + quad*4 + r;
        int jout = t*16 + l16;
        atomicAdd(&Rs[base + iout*64 + jout], acc[s][t][r]);
      }
    }
  }
}

// ---------------------------------------------------------------------------
// k_rmerge: expand Rstage (41 shifts) into full symmetric R (81 uv).
// ---------------------------------------------------------------------------
__global__ __launch_bounds__(256) void k_rmerge(float* __restrict__ ws) {
  int idx = blockIdx.x*256 + threadIdx.x;    // 1,327,104 total
  int uv = idx % 81;
  int rem = idx / 81;
  int j = rem & 63;
  int i = (rem >> 6) & 63;
  int n = rem >> 12;
  int s, si, sj;
  if (uv >= 40) { s = uv - 40; si = i; sj = j; }
  else          { s = 40 - uv; si = j; sj = i; }
  ws[OFF_R + idx] = ws[OFF_RP + ((size_t)n*41 + s)*4096 + si*64 + sj];
}

// ---------------------------------------------------------------------------
// Pm -> CG initial state: RV = PV = Pm (rr computed in-block by CG steps)
// ---------------------------------------------------------------------------
__global__ __launch_bounds__(256) void k_pm(const float* __restrict__ xn,
                                            const float* __restrict__ y,
                                            const float* __restrict__ dict,
                                            const float* __restrict__ alpha_d,
                                            const float* __restrict__ regp,
                                            float* __restrict__ ws) {
  __shared__ float xt[20*20];
  __shared__ float red_s[4][25];
  int n = blockIdx.y, i = blockIdx.x, tid = threadIdx.x;
  int py = tid >> 4, px = tid & 15;
  float acc[25];
#pragma unroll
  for (int t = 0; t < 25; ++t) acc[t] = 0.0f;
  const float* Xi = xn + (size_t)(n*CIN + i)*NPIX;
  for (int tile = 0; tile < 64; ++tile) {
    int h0 = (tile >> 3)*16, w0 = (tile & 7)*16;
    __syncthreads();
    for (int t = tid; t < 400; t += 256) {
      int r = t / 20, cc = t % 20;
      int gh = h0 + r - 2, gw = w0 + cc - 2;
      float v = 0.0f;
      if (gh >= 0 && gh < 128 && gw >= 0 && gw < 128) v = Xi[gh*128 + gw];
      xt[t] = v;
    }
    __syncthreads();
    float yv = y[(n*HH + h0 + py)*WW + w0 + px];
#pragma unroll
    for (int u = 0; u < 5; ++u)
#pragma unroll
      for (int v = 0; v < 5; ++v)
        acc[u*5+v] += xt[(py+u)*20 + (px+v)] * yv;
  }
  int lane = tid & 63, wv = tid >> 6;
#pragma unroll
  for (int t = 0; t < 25; ++t) {
    float v = acc[t];
    WRED(v);
    if (lane == 0) red_s[wv][t] = v;
  }
  __syncthreads();
  if (tid < 25) {
    float s = red_s[0][tid] + red_s[1][tid] + red_s[2][tid] + red_s[3][tid];
    float ad = alpha_d[n] * 16384.0f * regp[0] * (1.0f/1600.0f);
    float val = s + ad * dict[(n*CIN + i)*25 + tid];
    int idx = n*MMAT + i*25 + tid;
    ws[OFF_RV + idx] = val;
    ws[OFF_PV + idx] = val;
  }
}

// ---------------------------------------------------------------------------
// CG: k_cg_first computes Ap0 + pAp0 partials (per j, no atomics).
// ---------------------------------------------------------------------------
__global__ __launch_bounds__(256) void k_cg_first(float* __restrict__ ws,
                                                  const float* __restrict__ alpha_d,
                                                  const float* __restrict__ regp) {
  __shared__ float vv[MMAT];
  __shared__ float part[25][66];
  int n = blockIdx.y, j = blockIdx.x, tid = threadIdx.x;
  for (int t = tid; t < MMAT; t += 256) vv[t] = ws[OFF_PV + n*MMAT + t];
  __syncthreads();
  int i = tid & 63, qq = tid >> 6;
  const float* Rij = ws + OFF_R + (((size_t)n*CIN + i)*CIN + j)*81;
  const float* vi = &vv[i*25];
#pragma unroll
  for (int s6 = 0; s6 < 7; ++s6) {
    int ac = qq + 4*s6;
    if (ac < 25) {
      int a = ac/5, c = ac%5;
      float s = 0.0f;
#pragma unroll
      for (int b = 0; b < 5; ++b)
#pragma unroll
        for (int d = 0; d < 5; ++d)
          s += Rij[(4+b-a)*9 + (4+d-c)] * vi[b*5+d];
      part[ac][i] = s;
    }
  }
  __syncthreads();
  float contrib = 0.0f;
  if (tid < 25) {
    float s = 0.0f;
    for (int t = 0; t < 64; ++t) s += part[tid][t];
    float reg = alpha_d[n] * 16384.0f * regp[0] * (1.0f/1600.0f);
    s += reg * vv[j*25 + tid];
    ws[OFF_AP + n*MMAT + j*25 + tid] = s;
    contrib = s * vv[j*25 + tid];
  }
  if (tid < 64) {
    WRED(contrib);
    if (tid == 0) ws[OFF_PAPP + 0*256 + n*64 + j] = contrib;
  }
}

// ---------------------------------------------------------------------------
// Fused CG step: full r in LDS; rr/alpha/beta in-block (identical across
// blocks); matvec A r_new; updates 25-elem segments; pAp partial per j.
// RV double-buffered by iteration parity -> race-free across blocks.
// ---------------------------------------------------------------------------
__global__ __launch_bounds__(256) void k_cg_step(float* __restrict__ ws, int it,
                                                 int last, float* __restrict__ out,
                                                 const float* __restrict__ alpha_d,
                                                 const float* __restrict__ regp) {
  __shared__ float vv[MMAT];       // r_new
  __shared__ float red_s[9];
  __shared__ float part[25][66];
  int n = blockIdx.y, j = blockIdx.x, tid = threadIdx.x;
  const float* rsrc = ws + ((it & 1) ? OFF_RV2 : OFF_RV) + n*MMAT;
  float*       rdst = ws + ((it & 1) ? OFF_RV  : OFF_RV2) + n*MMAT;
  int lane = tid & 63, wvi = tid >> 6;

  float rold[7], apv[7];
  float rrp = 0.0f;
#pragma unroll
  for (int t = 0; t < 7; ++t) {
    int idx = tid + 256*t;
    rold[t] = 0.0f; apv[t] = 0.0f;
    if (idx < MMAT) {
      rold[t] = rsrc[idx];
      apv[t]  = ws[OFF_AP + n*MMAT + idx];
      rrp += rold[t]*rold[t];
    }
  }
  WRED(rrp);
  if (lane == 0) red_s[wvi] = rrp;
  float pp = (tid < 64) ? ws[OFF_PAPP + it*256 + n*64 + tid] : 0.0f;
  if (tid < 64) { WRED(pp); if (tid == 0) red_s[4] = pp; }
  __syncthreads();
  float rr_old = red_s[0] + red_s[1] + red_s[2] + red_s[3];
  float alpha = rr_old / (red_s[4] + 1e-30f);

  if (last) {
    if (tid < 25) {
      int idx = n*MMAT + j*25 + tid;
      float dv = ws[OFF_DV + idx] + alpha * ws[OFF_PV + idx];
      out[4194304 + n*MMAT + j*25 + tid] = dv;
    }
    return;
  }

  float rrnp = 0.0f;
#pragma unroll
  for (int t = 0; t < 7; ++t) {
    int idx = tid + 256*t;
    if (idx < MMAT) {
      float rn = rold[t] - alpha * apv[t];
      vv[idx] = rn;
      rrnp += rn*rn;
    }
  }
  WRED(rrnp);
  __syncthreads();                           // vv complete
  if (lane == 0) red_s[5 + wvi] = rrnp;
  __syncthreads();
  float rr_new = red_s[5] + red_s[6] + red_s[7] + red_s[8];
  float beta = rr_new / (rr_old + 1e-30f);

  int i = tid & 63, qq = tid >> 6;
  const float* Rij = ws + OFF_R + (((size_t)n*CIN + i)*CIN + j)*81;
  const float* vi = &vv[i*25];
#pragma unroll
  for (int s6 = 0; s6 < 7; ++s6) {
    int ac = qq + 4*s6;
    if (ac < 25) {
      int a = ac/5, c = ac%5;
      float s = 0.0f;
#pragma unroll
      for (int b = 0; b < 5; ++b)
#pragma unroll
        for (int d = 0; d < 5; ++d)
          s += Rij[(4+b-a)*9 + (4+d-c)] * vi[b*5+d];
      part[ac][i] = s;
    }
  }
  __syncthreads();
  float contrib = 0.0f;
  if (tid < 25) {
    float s = 0.0f;
    for (int t = 0; t < 64; ++t) s += part[tid][t];
    float reg = alpha_d[n] * 16384.0f * regp[0] * (1.0f/1600.0f);
    float rn_seg = vv[j*25 + tid];
    s += reg * rn_seg;
    int idx = n*MMAT + j*25 + tid;
    float p_old = ws[OFF_PV + idx];
    float dv = ws[OFF_DV + idx] + alpha * p_old;
    float pn  = rn_seg + beta * p_old;
    float apn = s + beta * ws[OFF_AP + idx];
    ws[OFF_DV + idx] = dv;
    ws[OFF_PV + idx] = pn;
    ws[OFF_AP + idx] = apn;
    rdst[j*25 + tid] = rn_seg;
    contrib = pn * apn;
  }
  if (tid < 64) {
    WRED(contrib);
    if (tid == 0) ws[OFF_PAPP + (it+1)*256 + n*64 + j] = contrib;
  }
}

// ---------------------------------------------------------------------------
extern "C" void kernel_launch(void* const* d_in, const int* in_sizes, int n_in,
                              void* d_out, int out_size, void* d_ws, size_t ws_size,
                              hipStream_t stream) {
  (void)in_sizes; (void)n_in; (void)out_size; (void)ws_size;
  const float* x    = (const float*)d_in[0];
  const float* dict = (const float*)d_in[1];
  const float* y    = (const float*)d_in[2];
  const float* ax   = (const float*)d_in[3];
  const float* ad   = (const float*)d_in[4];
  const float* regp = (const float*)d_in[5];
  float* out = (float*)d_out;
  float* ws  = (float*)d_ws;

  dim3 b256(256);
  k_sinv<<<dim3(33,4), b256, 0, stream>>>(dict, ax, ws);
  k_e<<<dim3(64,4), b256, 0, stream>>>(x, dict, y, ws);
  k_fft_rows<<<dim3(33,4), b256, 0, stream>>>(ws);
  k_fft_colpipe<<<dim3(65,4), dim3(128), 0, stream>>>(ws);
  k_ifft_rows<<<dim3(64,4), b256, 0, stream>>>(ws);
  k_xnew<<<dim3(64,4), b256, 0, stream>>>(x, dict, ws, out);

  // ---- R via MFMA: pad, zero stage, shift-GEMM (atomic accumulate), merge
  k_pad<<<dim3(73,256), b256, 0, stream>>>(out, ws);
  k_rzero<<<dim3(657), b256, 0, stream>>>(ws);
  k_gemm<<<dim3(11,16,4), b256, 0, stream>>>(ws);
  k_rmerge<<<dim3(5184), b256, 0, stream>>>(ws);

  k_pm<<<dim3(64,4), b256, 0, stream>>>(out, y, dict, ad, regp, ws);

  // ---- CG (fused steps; 7 launches) ----
  k_cg_first<<<dim3(64,4), b256, 0, stream>>>(ws, ad, regp);
  for (int it = 0; it < NIT; ++it)
    k_cg_step<<<dim3(64,4), b256, 0, stream>>>(ws, it, (it == NIT-1) ? 1 : 0, out, ad, regp);
}